// Round 16
// baseline (67.797 us; speedup 1.0000x reference)
//
#include <hip/hip_runtime.h>
#include <stdint.h>

typedef unsigned long long u64;
typedef unsigned int u32;

#define N_PIX (512*512)
#define KW 512
#define KC 2048
#define CAPW 4096
#define CAPC 4096
#define NUM_CLS 68
#define WORD_THR 0.5f
#define CHAR_THR 0.25f
#define IOU_THR 0.3f
#define NBLK 128
#define BS 512
#define GSZ (NBLK*BS)        // 65536 threads; exactly N_PIX/4 float4s; 2048 px/block
#define BASE16W 0x3F00u      // top16 of f32 in (0.5,1)  -> [0x3F00,0x3F80)
#define BASE16C 0x3E80u      // top16 of f32 in (0.25,1) -> [0x3E80,0x3F80)

struct SelState { u64 prefix; u32 kRem; u32 counter; u32 hist[256]; };

__device__ __forceinline__ u64 mk_key(u32 fb, u32 i){
  return (((u64)fb) << 32) | (u64)(0xFFFFFFFFu - i);
}

__global__ void k0_init(SelState* stW, SelState* stC, u32* bars){
  int t = threadIdx.x;
  if (t==0){ stW->prefix=0ull; stW->kRem=KW; stW->counter=0u; }
  if (t==1){ stC->prefix=0ull; stC->kRem=KC; stC->counter=0u; }
  if (t < 8) bars[t] = 0u;
  stW->hist[t]=0u; stC->hist[t]=0u;   // 256 threads
}

// 64-lane scan of 256-bin hist (descending): largest digit d with suffix-count >= kRem.
__device__ __forceinline__ void scan_wave(SelState* st, u32 base16, int lane){
  u32 h[4];
  #pragma unroll
  for (int q=0;q<4;q++)
    h[q] = __hip_atomic_load(&st->hist[lane*4+q], __ATOMIC_RELAXED, __HIP_MEMORY_SCOPE_AGENT);
  u32 lsum = h[0]+h[1]+h[2]+h[3];
  u32 v = lsum;
  #pragma unroll
  for (int off=1; off<64; off<<=1){
    u32 t2 = __shfl_down(v, off, 64);
    if (lane + off < 64) v += t2;
  }
  u32 above = v - lsum;                 // sum over lanes > lane
  u32 k = st->kRem;
  u32 sfx1 = h[3]+h[2]+h[1], sfx2 = h[3]+h[2], sfx3 = h[3];
  int best = -1;
  if      (above + sfx3 >= k) best = lane*4+3;
  else if (above + sfx2 >= k) best = lane*4+2;
  else if (above + sfx1 >= k) best = lane*4+1;
  else if (above + lsum >= k) best = lane*4+0;
  u64 m = __ballot(best >= 0);
  int d = 0;
  if (m != 0ull){
    int hi_lane = 63 - __clzll(m);
    d = __shfl(best, hi_lane, 64);
  }
  if (lane==0)
    __hip_atomic_store(&st->prefix, ((u64)(base16 + (u32)d)) << 48,
                       __ATOMIC_RELAXED, __HIP_MEMORY_SCOPE_AGENT);
}

// D1: one float4 image pass -> hist + LDS key stash; done-counter; last block scans +
//     sentinel release; all blocks filter stash and compact (2 global atomics/block).
__global__ __launch_bounds__(BS)
void k1_histcompact(const float* __restrict__ wfg, const float* __restrict__ cfg,
                    SelState* stW, SelState* stC, u32* bars, u32* ranks,
                    u64* candW, u64* candC){
  __shared__ u32 hW[256], hC[256];
  __shared__ u64 lkW[2048], lkC[2048];     // stash: 2048 px/block -> no overflow
  __shared__ u64 outW[256], outC[256];
  __shared__ u32 lcW, lcC, ocW, ocC, baseW, baseC;
  __shared__ int isLast;
  const int tid = threadIdx.x;
  const int gtid = blockIdx.x*BS + tid;
  const int lane = tid & 63;
  const u64 lmlt = (1ull << lane) - 1ull;
  if (gtid < CAPW+CAPC) ranks[gtid] = 0u;
  if (tid < 256){ hW[tid]=0u; hC[tid]=0u; }
  if (tid==0){ lcW=0u; lcC=0u; ocW=0u; ocC=0u; }
  __syncthreads();
  // ---- capture + hist ----
  {
    float4 wv4 = ((const float4*)wfg)[gtid];
    float4 cv4 = ((const float4*)cfg)[gtid];
    #pragma unroll
    for (int q=0;q<4;q++){
      float wf = q==0?wv4.x:(q==1?wv4.y:(q==2?wv4.z:wv4.w));
      float cf = q==0?cv4.x:(q==1?cv4.y:(q==2?cv4.z:cv4.w));
      u32 i = 4u*(u32)gtid + (u32)q;
      bool wp = wf > WORD_THR;
      u64 mW = __ballot(wp);
      if (mW){
        u32 base;
        int ldr = __ffsll(mW) - 1;
        if (lane == ldr) base = atomicAdd(&lcW, (u32)__popcll(mW));
        base = __shfl(base, ldr, 64);
        if (wp){
          u32 fb = __float_as_uint(wf);
          lkW[base + (u32)__popcll(mW & lmlt)] = mk_key(fb, i);
          atomicAdd(&hW[(fb>>16) - BASE16W], 1u);
        }
      }
      bool cp = wp && (cf > CHAR_THR);
      u64 mC = __ballot(cp);
      if (mC){
        u32 base;
        int ldr = __ffsll(mC) - 1;
        if (lane == ldr) base = atomicAdd(&lcC, (u32)__popcll(mC));
        base = __shfl(base, ldr, 64);
        if (cp){
          u32 fb = __float_as_uint(cf);
          lkC[base + (u32)__popcll(mC & lmlt)] = mk_key(fb, i);
          atomicAdd(&hC[(fb>>16) - BASE16C], 1u);
        }
      }
    }
  }
  __syncthreads();
  if (tid < 256){
    if (hW[tid]) atomicAdd(&stW->hist[tid], hW[tid]);
    if (hC[tid]) atomicAdd(&stC->hist[tid], hC[tid]);
  }
  // ---- done-counter; last block scans + releases sentinel ----
  __syncthreads();
  if (tid==0){
    u32 p = __hip_atomic_fetch_add(&bars[0],1u,__ATOMIC_ACQ_REL,__HIP_MEMORY_SCOPE_AGENT);
    isLast = (p == NBLK-1);
  }
  __syncthreads();
  if (isLast){
    if (tid < 128){
      if (tid < 64) scan_wave(stW, BASE16W, lane);
      else          scan_wave(stC, BASE16C, lane);
    }
    __syncthreads();
    if (tid==0)
      __hip_atomic_store(&bars[0], 0xFFFFFFFFu, __ATOMIC_RELEASE, __HIP_MEMORY_SCOPE_AGENT);
  } else if (tid==0){
    while (__hip_atomic_load(&bars[0], __ATOMIC_ACQUIRE, __HIP_MEMORY_SCOPE_AGENT) != 0xFFFFFFFFu)
      __builtin_amdgcn_s_sleep(2);
  }
  __syncthreads();
  // ---- filter stash by threshold into out lists ----
  {
    u64 tW = __hip_atomic_load(&stW->prefix, __ATOMIC_RELAXED, __HIP_MEMORY_SCOPE_AGENT);
    u64 tC = __hip_atomic_load(&stC->prefix, __ATOMIC_RELAXED, __HIP_MEMORY_SCOPE_AGENT);
    u32 nW = lcW, nC = lcC;
    for (u32 b = 0; b < nW; b += BS){
      u32 t = b + tid;
      bool act = (t < nW);
      u64 k = act ? lkW[t] : 0ull;
      bool pw = act && (k >= tW);
      u64 m = __ballot(pw);
      if (m){
        u32 base;
        int ldr = __ffsll(m) - 1;
        if (lane == ldr) base = atomicAdd(&ocW, (u32)__popcll(m));
        base = __shfl(base, ldr, 64);
        if (pw){ u32 p = base + (u32)__popcll(m & lmlt); if (p < 256) outW[p] = k; }
      }
    }
    for (u32 b = 0; b < nC; b += BS){
      u32 t = b + tid;
      bool act = (t < nC);
      u64 k = act ? lkC[t] : 0ull;
      bool pc = act && (k >= tC);
      u64 m = __ballot(pc);
      if (m){
        u32 base;
        int ldr = __ffsll(m) - 1;
        if (lane == ldr) base = atomicAdd(&ocC, (u32)__popcll(m));
        base = __shfl(base, ldr, 64);
        if (pc){ u32 p = base + (u32)__popcll(m & lmlt); if (p < 256) outC[p] = k; }
      }
    }
  }
  __syncthreads();
  if (tid==0)      baseW = atomicAdd(&stW->counter, min(ocW,256u));
  else if (tid==1) baseC = atomicAdd(&stC->counter, min(ocC,256u));
  __syncthreads();
  {
    u32 nW = min(ocW,256u), nC = min(ocC,256u);
    for (u32 t = tid; t < nW; t += BS){ u32 p = baseW + t; if (p < CAPW) candW[p] = outW[t]; }
    for (u32 t = tid; t < nC; t += BS){ u32 p = baseC + t; if (p < CAPC) candC[p] = outC[t]; }
  }
}

// D2: {boxes->regs (wave0, 64 slots/block) || rank tiles (all)} -> bar -> register permute
__global__ __launch_bounds__(BS)
void k3_rank(SelState* stW, SelState* stC, u64* candW, u64* candC, u32* ranks, u32* bars,
             const float* __restrict__ wtblr, const float* __restrict__ worient,
             const float* __restrict__ ctblr,
             const int* p_sw, const int* p_sh, const int* p_ow, const int* p_oh,
             u64* sortedW, u64* sortedC, float4* aabbW, float4* aabbC,
             float* out_wb, float* out_cb){
  __shared__ u64 chunk[256];
  const int tid = threadIdx.x;
  u32 CW = stW->counter; if (CW > CAPW) CW = CAPW;
  u32 CC = stC->counter; if (CC > CAPC) CC = CAPC;
  // ---- boxes for this block's 64 slots -> registers (wave 0 only) ----
  bool live = false; bool myW = false; u64 my = 0ull;
  float bx0,bx1,bx2,bx3,bx4,bx5,bx6,bx7,bx8;
  float4 av;
  if (tid < 64){
    int t = blockIdx.x*64 + tid;            // 128*64 == CAPW+CAPC exactly
    myW = (t < CAPW);
    int slot = myW ? t : t - CAPW;
    u32 C = myW ? CW : CC;
    if (slot < (int)C){
      live = true;
      my = (myW ? candW : candC)[slot];
      u32 idx = 0xFFFFFFFFu - (u32)(my & 0xFFFFFFFFull);
      float score = __uint_as_float((u32)(my>>32));
      float swf = (float)(*p_sw) * 4.0f;    // WORD_STRIDE == CHAR_STRIDE == 4
      float shf = (float)(*p_sh) * 4.0f;
      float owm = (float)(*p_ow) - 1.0f, ohm = (float)(*p_oh) - 1.0f;
      const float* tblr = myW ? wtblr : ctblr;
      float tt2 = tblr[idx], bb = tblr[N_PIX+idx], ll = tblr[2*N_PIX+idx], rr = tblr[3*N_PIX+idx];
      float xf = (float)(idx & 511u), yf = (float)(idx >> 9);
      float c = 1.0f, sn = 0.0f;
      if (myW){ float o = worient[idx]; c = cosf(o); sn = sinf(o); }
      float x1 = swf*(xf - ll), x2 = swf*(xf + rr);
      float y1 = shf*(yf - tt2), y2 = shf*(yf + bb);
      float ax = swf*xf, ay = shf*yf;
      float cx[4] = {x1,x2,x2,x1};
      float cy[4] = {y1,y1,y2,y2};
      float rx[4], ry[4];
      #pragma unroll
      for (int q=0;q<4;q++){
        float dx = cx[q]-ax, dy = cy[q]-ay;
        rx[q] = ax + dx*c - dy*sn;
        ry[q] = ay + dx*sn + dy*c;
      }
      float minx = fminf(fminf(rx[0],rx[1]),fminf(rx[2],rx[3]));
      float maxx = fmaxf(fmaxf(rx[0],rx[1]),fmaxf(rx[2],rx[3]));
      float miny = fminf(fminf(ry[0],ry[1]),fminf(ry[2],ry[3]));
      float maxy = fmaxf(fmaxf(ry[0],ry[1]),fmaxf(ry[2],ry[3]));
      av = make_float4(minx,miny,maxx,maxy);
      bx0 = fminf(fmaxf(rintf(rx[0]),0.0f), owm); bx1 = fminf(fmaxf(rintf(ry[0]),0.0f), ohm);
      bx2 = fminf(fmaxf(rintf(rx[1]),0.0f), owm); bx3 = fminf(fmaxf(rintf(ry[1]),0.0f), ohm);
      bx4 = fminf(fmaxf(rintf(rx[2]),0.0f), owm); bx5 = fminf(fmaxf(rintf(ry[2]),0.0f), ohm);
      bx6 = fminf(fmaxf(rintf(rx[3]),0.0f), owm); bx7 = fminf(fmaxf(rintf(ry[3]),0.0f), ohm);
      bx8 = score;
    }
  }
  // ---- tiled rank count: 512-slot groups x 256-key chunks, whole grid ----
  {
    int gW = (int)((CW + 511) >> 9), hW = (int)((CW + 255) >> 8);
    int gC = (int)((CC + 511) >> 9), hC = (int)((CC + 255) >> 8);
    int tilesW = gW*hW, tiles = tilesW + gC*hC;
    for (int t = blockIdx.x; t < tiles; t += NBLK){
      bool isW = (t < tilesW);
      int tt = isW ? t : t - tilesW;
      int h  = isW ? hW : hC;
      u32 C  = isW ? CW : CC;
      const u64* cand = isW ? candW : candC;
      u32* rk = isW ? ranks : (ranks + CAPW);
      int sg = tt / h, ch = tt - sg*h;
      __syncthreads();                      // LDS reuse guard
      if (tid < 256){ int ci = ch*256 + tid; chunk[tid] = (ci < (int)C) ? cand[ci] : 0ull; }
      __syncthreads();
      int slot = sg*BS + tid;
      if (slot < (int)C){
        u64 m2 = cand[slot];
        int cnt = 0;
        const ulonglong2* cp = (const ulonglong2*)chunk;
        #pragma unroll 8
        for (int i2=0;i2<128;i2++){ ulonglong2 v = cp[i2]; cnt += (v.x > m2) + (v.y > m2); }
        if (cnt) atomicAdd(&rk[slot], (u32)cnt);
      }
    }
  }
  // ---- full barrier (ranks complete) ----
  __syncthreads();
  if (tid==0){
    __hip_atomic_fetch_add(&bars[3],1u,__ATOMIC_ACQ_REL,__HIP_MEMORY_SCOPE_AGENT);
    while (__hip_atomic_load(&bars[3], __ATOMIC_ACQUIRE, __HIP_MEMORY_SCOPE_AGENT) < (u32)NBLK)
      __builtin_amdgcn_s_sleep(2);
  }
  __syncthreads();
  // ---- permute from registers to sorted order ----
  if (live){
    int t = blockIdx.x*64 + tid;
    int rank = (int)ranks[t];
    int K = myW ? KW : KC;
    if (rank < K){
      (myW ? sortedW : sortedC)[rank] = my;
      (myW ? aabbW : aabbC)[rank] = av;
      float* ob = myW ? out_wb : out_cb;
      ob[rank*9+0]=bx0; ob[rank*9+1]=bx1; ob[rank*9+2]=bx2; ob[rank*9+3]=bx3;
      ob[rank*9+4]=bx4; ob[rank*9+5]=bx5; ob[rank*9+6]=bx6; ob[rank*9+7]=bx7;
      ob[rank*9+8]=bx8;
    }
  }
}

template<int W>
__device__ __forceinline__ void sup_row(int j, int lane, const float4* __restrict__ aabb,
                                        u64* __restrict__ supT, u32* __restrict__ rm){
  float4 bj = aabb[j];
  float aj = fmaxf(bj.z-bj.x,0.0f)*fmaxf(bj.w-bj.y,0.0f);
  u32 m = 0;
  #pragma unroll 4
  for (int w=0; w<W; w++){
    int i = w*64 + lane;
    float4 bi = aabb[i];
    float ai = fmaxf(bi.z-bi.x,0.0f)*fmaxf(bi.w-bi.y,0.0f);
    float ix1=fmaxf(bi.x,bj.x), iy1=fmaxf(bi.y,bj.y);
    float ix2=fminf(bi.z,bj.z), iy2=fminf(bi.w,bj.w);
    float inter = fmaxf(ix2-ix1,0.0f)*fmaxf(iy2-iy1,0.0f);
    float iou = inter/(ai+aj-inter+1e-6f);
    bool bit = (iou > IOU_THR) && (i < j);
    u64 b = __ballot(bit);
    if (b){ if (lane==0) supT[(size_t)j*W + w] = b; m |= 1u << w; }
  }
  if (lane==0) rm[j] = m;
}

// NMS Jacobi fixpoint (unique fixed point == greedy NMS result)
template<int K, int W>
__device__ void nms_body(u64* kw, int* changed,
                         const u64* __restrict__ supT, const u32* __restrict__ rm,
                         const u64* __restrict__ sorted, float* __restrict__ keep){
  const int tid = threadIdx.x;
  const int lane = tid & 63, wv = tid >> 6;
  constexpr int NB = (K + BS - 1)/BS;
  if (tid < W) kw[tid] = ~0ull;
  __syncthreads();
  for(;;){
    if (tid==0) *changed = 0;
    __syncthreads();
    bool nb[NB];
    #pragma unroll
    for (int q=0;q<NB;q++){
      int j = q*BS + tid;
      bool ok = (j < K);
      u64 su = 0ull;
      if (ok){
        u32 m = rm[j];
        while (m){ int w = __ffs(m)-1; m &= m-1u; su |= supT[(size_t)j*W + w] & kw[w]; }
      }
      nb[q] = ok && (su == 0ull);
    }
    __syncthreads();
    #pragma unroll
    for (int q=0;q<NB;q++){
      int wi = q*(BS/64) + wv;
      u64 b = __ballot(nb[q]);
      if (lane==0 && wi < W){
        if (b != kw[wi]){ kw[wi] = b; *changed = 1; }
      }
    }
    __syncthreads();
    int ch = *changed;
    __syncthreads();
    if (!ch) break;
  }
  #pragma unroll
  for (int q=0;q<NB;q++){
    int j = q*BS + tid;
    if (j < K){
      u64 key = sorted[j];
      bool pos = ((u32)(key>>32)) != 0u;
      bool kp = (((kw[j>>6] >> (j&63)) & 1ull) != 0ull) && pos;
      keep[j] = kp ? 1.0f : 0.0f;
    }
  }
}

// D3: sup (all blocks) -> arrival -> {blocks >=2: class gather, exit | blocks 0,1: nms}
//     nms overlaps the gather (supT is L2-resident; gather streams HBM)
__global__ __launch_bounds__(BS)
void k4_tail(const float4* __restrict__ aabbW, const float4* __restrict__ aabbC,
             u64* supTW, u64* supTC, u32* rmW, u32* rmC, u32* bars,
             const u64* __restrict__ sortedW, const u64* __restrict__ sortedC,
             const float* __restrict__ ccls, float* __restrict__ out_cs,
             float* out_wk, float* out_ck){
  __shared__ u64 kw[KC/64];
  __shared__ int changed;
  const int tid = threadIdx.x;
  const int gtid = blockIdx.x*BS + tid;
  const int lane = tid & 63;
  int gw = gtid >> 6;                        // 1024 waves, 2-3 rows each
  for (int row = gw; row < KW+KC; row += GSZ/64){
    if (row < KW) sup_row<KW/64>(row, lane, aabbW, supTW, rmW);
    else          sup_row<KC/64>(row-KW, lane, aabbC, supTC, rmC);
  }
  __syncthreads();
  if (tid==0) __hip_atomic_fetch_add(&bars[2],1u,__ATOMIC_ACQ_REL,__HIP_MEMORY_SCOPE_AGENT);
  if (blockIdx.x >= 2){
    // class gather after arrival: overlaps the nms fixpoint on blocks 0/1
    for (int t = (blockIdx.x-2)*BS + tid; t < KC*NUM_CLS; t += (NBLK-2)*BS){
      int k = t / NUM_CLS;
      int c = t - k*NUM_CLS;
      u32 idx = 0xFFFFFFFFu - (u32)(sortedC[k] & 0xFFFFFFFFull);
      out_cs[t] = ccls[(size_t)c*N_PIX + idx];
    }
    return;
  }
  if (tid==0){
    while (__hip_atomic_load(&bars[2], __ATOMIC_ACQUIRE, __HIP_MEMORY_SCOPE_AGENT) < (u32)NBLK)
      __builtin_amdgcn_s_sleep(2);
  }
  __syncthreads();
  if (blockIdx.x == 0) nms_body<KW, KW/64>(kw, &changed, supTW, rmW, sortedW, out_wk);
  else                 nms_body<KC, KC/64>(kw, &changed, supTC, rmC, sortedC, out_ck);
}

extern "C" void kernel_launch(void* const* d_in, const int* in_sizes, int n_in,
                              void* d_out, int out_size, void* d_ws, size_t ws_size,
                              hipStream_t stream) {
  const float* wfg     = (const float*)d_in[0];
  const float* wtblr   = (const float*)d_in[1];
  const float* worient = (const float*)d_in[2];
  const float* cfg     = (const float*)d_in[3];
  const float* ctblr   = (const float*)d_in[4];
  const float* ccls    = (const float*)d_in[5];
  const int* p_sw = (const int*)d_in[6];
  const int* p_sh = (const int*)d_in[7];
  const int* p_ow = (const int*)d_in[8];
  const int* p_oh = (const int*)d_in[9];

  // ws layout (phase-overlayed; all accesses < 631824 B)
  char* ws = (char*)d_ws;
  u64* candW   = (u64*)(ws + 0);        // dies after k3_rank; then supTW
  u64* candC   = (u64*)(ws + 32768);    // dies after k3_rank; then supTC
  u64* supTW   = (u64*)(ws + 0);
  u64* supTC   = (u64*)(ws + 32768);    // spans to 557056
  u32* ranks   = (u32*)(ws + 65536);    // [CAPW+CAPC]; dies after k3_rank (under supTC span)
  u64* sortedW = (u64*)(ws + 557056);
  u64* sortedC = (u64*)(ws + 561152);
  float4* aabbW= (float4*)(ws + 577536);
  float4* aabbC= (float4*)(ws + 585728);
  u32* rmW     = (u32*)(ws + 618496);
  u32* rmC     = (u32*)(ws + 620544);
  SelState* stW= (SelState*)(ws + 628736);
  u32* bars    = (u32*)(ws + 630016);
  SelState* stC= (SelState*)(ws + 630784);

  float* out = (float*)d_out;
  float* out_cb = out;                          // char bboxes 2048*9
  float* out_cs = out + KC*9;                   // char scores 2048*68
  float* out_wb = out + KC*9 + KC*NUM_CLS;      // word bboxes 512*9
  float* out_wk = out_wb + KW*9;                // wkeep 512
  float* out_ck = out_wk + KW;                  // ckeep 2048

  k0_init<<<1, 256, 0, stream>>>(stW, stC, bars);
  k1_histcompact<<<NBLK, BS, 0, stream>>>(wfg, cfg, stW, stC, bars, ranks, candW, candC);
  k3_rank<<<NBLK, BS, 0, stream>>>(stW, stC, candW, candC, ranks, bars,
                                   wtblr, worient, ctblr, p_sw, p_sh, p_ow, p_oh,
                                   sortedW, sortedC, aabbW, aabbC, out_wb, out_cb);
  k4_tail<<<NBLK, BS, 0, stream>>>(aabbW, aabbC, supTW, supTC, rmW, rmC, bars,
                                   sortedW, sortedC, ccls, out_cs, out_wk, out_ck);
}

// Round 17
// 64.047 us; speedup vs baseline: 1.0586x; 1.0586x over previous
//
#include <hip/hip_runtime.h>
#include <stdint.h>

typedef unsigned long long u64;
typedef unsigned int u32;

#define N_PIX (512*512)
#define KW 512
#define KC 2048
#define CAPW 4096
#define CAPC 4096
#define NUM_CLS 68
#define WORD_THR 0.5f
#define CHAR_THR 0.25f
#define IOU_THR 0.3f
#define NBLK 128
#define BS 512
#define GSZ (NBLK*BS)        // 65536 threads; exactly N_PIX/4 float4s
#define LKW 256              // per-block key stash caps (Poisson mean ~8 / ~18)
#define LKC 256
#define BASE16W 0x3F00u      // top16 of f32 in (0.5,1)  -> [0x3F00,0x3F80)
#define BASE16C 0x3E80u      // top16 of f32 in (0.25,1) -> [0x3E80,0x3F80)

struct SelState { u64 prefix; u32 kRem; u32 counter; u32 hist[256]; };

__device__ __forceinline__ u64 mk_key(u32 fb, u32 i){
  return (((u64)fb) << 32) | (u64)(0xFFFFFFFFu - i);
}

__global__ void k0_init(SelState* stW, SelState* stC, u32* bars){
  int t = threadIdx.x;
  if (t==0){ stW->prefix=0ull; stW->kRem=KW; stW->counter=0u; }
  if (t==1){ stC->prefix=0ull; stC->kRem=KC; stC->counter=0u; }
  if (t < 8) bars[t] = 0u;
  stW->hist[t]=0u; stC->hist[t]=0u;   // 256 threads
}

// 64-lane scan of 256-bin hist (descending): largest digit d with suffix-count >= kRem.
__device__ __forceinline__ void scan_wave(SelState* st, u32 base16, int lane){
  u32 h[4];
  #pragma unroll
  for (int q=0;q<4;q++)
    h[q] = __hip_atomic_load(&st->hist[lane*4+q], __ATOMIC_RELAXED, __HIP_MEMORY_SCOPE_AGENT);
  u32 lsum = h[0]+h[1]+h[2]+h[3];
  u32 v = lsum;
  #pragma unroll
  for (int off=1; off<64; off<<=1){
    u32 t2 = __shfl_down(v, off, 64);
    if (lane + off < 64) v += t2;
  }
  u32 above = v - lsum;                 // sum over lanes > lane
  u32 k = st->kRem;
  u32 sfx1 = h[3]+h[2]+h[1], sfx2 = h[3]+h[2], sfx3 = h[3];
  int best = -1;
  if      (above + sfx3 >= k) best = lane*4+3;
  else if (above + sfx2 >= k) best = lane*4+2;
  else if (above + sfx1 >= k) best = lane*4+1;
  else if (above + lsum >= k) best = lane*4+0;
  u64 m = __ballot(best >= 0);
  int d = 0;
  if (m != 0ull){
    int hi_lane = 63 - __clzll(m);
    d = __shfl(best, hi_lane, 64);
  }
  if (lane==0)
    __hip_atomic_store(&st->prefix, ((u64)(base16 + (u32)d)) << 48,
                       __ATOMIC_RELAXED, __HIP_MEMORY_SCOPE_AGENT);
}

// D1: one float4 image pass -> 256-bin top16 hist; last-done block scans. Also zeroes ranks[].
__global__ __launch_bounds__(BS)
void k1_hist(const float* __restrict__ wfg, const float* __restrict__ cfg,
             SelState* stW, SelState* stC, u32* bars, u32* ranks){
  __shared__ u32 hW[256], hC[256];
  __shared__ int isLast;
  const int tid = threadIdx.x;
  const int gtid = blockIdx.x*BS + tid;
  const int lane = tid & 63;
  if (gtid < CAPW+CAPC) ranks[gtid] = 0u;
  if (tid < 256){ hW[tid]=0u; hC[tid]=0u; }
  __syncthreads();
  float4 wv4 = ((const float4*)wfg)[gtid];
  float4 cv4 = ((const float4*)cfg)[gtid];
  #pragma unroll
  for (int q=0;q<4;q++){
    float wf = q==0?wv4.x:(q==1?wv4.y:(q==2?wv4.z:wv4.w));
    float cf = q==0?cv4.x:(q==1?cv4.y:(q==2?cv4.z:cv4.w));
    bool wp = wf > WORD_THR;
    if (wp) atomicAdd(&hW[(__float_as_uint(wf)>>16) - BASE16W], 1u);
    if (wp && cf > CHAR_THR) atomicAdd(&hC[(__float_as_uint(cf)>>16) - BASE16C], 1u);
  }
  __syncthreads();
  if (tid < 256){
    if (hW[tid]) atomicAdd(&stW->hist[tid], hW[tid]);
    if (hC[tid]) atomicAdd(&stC->hist[tid], hC[tid]);
  }
  __syncthreads();
  if (tid==0){
    u32 p = __hip_atomic_fetch_add(&bars[0],1u,__ATOMIC_ACQ_REL,__HIP_MEMORY_SCOPE_AGENT);
    isLast = (p == NBLK-1);
  }
  __syncthreads();
  if (isLast && tid < 128){
    if (tid < 64) scan_wave(stW, BASE16W, lane);
    else          scan_wave(stC, BASE16C, lane);
  }
}

// D2: block-local compact — LDS staging, 2 global atomics per block, coalesced copy-out.
__global__ __launch_bounds__(BS)
void k2_compact(const float* __restrict__ wfg, const float* __restrict__ cfg,
                SelState* stW, SelState* stC, u64* candW, u64* candC){
  __shared__ u64 lkW[LKW], lkC[LKC];
  __shared__ u32 lcW, lcC, baseW, baseC;
  const int tid = threadIdx.x;
  const int gtid = blockIdx.x*BS + tid;
  const int lane = tid & 63;
  const u64 lmlt = (1ull << lane) - 1ull;
  if (tid==0){ lcW = 0u; lcC = 0u; }
  __syncthreads();
  u64 tW = stW->prefix, tC = stC->prefix;
  float4 wv4 = ((const float4*)wfg)[gtid];
  float4 cv4 = ((const float4*)cfg)[gtid];
  #pragma unroll
  for (int q=0;q<4;q++){
    float wf = q==0?wv4.x:(q==1?wv4.y:(q==2?wv4.z:wv4.w));
    float cf = q==0?cv4.x:(q==1?cv4.y:(q==2?cv4.z:cv4.w));
    u32 i = 4u*(u32)gtid + (u32)q;
    bool wp = wf > WORD_THR;
    u64 kWd = mk_key(__float_as_uint(wf), i);
    bool pw = wp && (kWd >= tW);
    u64 mW = __ballot(pw);
    if (mW){
      u32 base;
      int ldr = __ffsll(mW) - 1;
      if (lane == ldr) base = atomicAdd(&lcW, (u32)__popcll(mW));
      base = __shfl(base, ldr, 64);
      if (pw){ u32 p = base + (u32)__popcll(mW & lmlt); if (p < LKW) lkW[p] = kWd; }
    }
    u64 kCh = mk_key(__float_as_uint(cf), i);
    bool pc = wp && (cf > CHAR_THR) && (kCh >= tC);
    u64 mC = __ballot(pc);
    if (mC){
      u32 base;
      int ldr = __ffsll(mC) - 1;
      if (lane == ldr) base = atomicAdd(&lcC, (u32)__popcll(mC));
      base = __shfl(base, ldr, 64);
      if (pc){ u32 p = base + (u32)__popcll(mC & lmlt); if (p < LKC) lkC[p] = kCh; }
    }
  }
  __syncthreads();
  if (tid==0)      baseW = atomicAdd(&stW->counter, min(lcW,(u32)LKW));
  else if (tid==1) baseC = atomicAdd(&stC->counter, min(lcC,(u32)LKC));
  __syncthreads();
  u32 nW = min(lcW,(u32)LKW), nC = min(lcC,(u32)LKC);
  for (u32 t = tid; t < nW; t += BS){ u32 p = baseW + t; if (p < CAPW) candW[p] = lkW[t]; }
  for (u32 t = tid; t < nC; t += BS){ u32 p = baseC + t; if (p < CAPC) candC[p] = lkC[t]; }
}

// D3: {boxes->regs (wave0, 64 slots/block) || rank tiles (all)} -> bar -> register permute
__global__ __launch_bounds__(BS)
void k3_rank(SelState* stW, SelState* stC, u64* candW, u64* candC, u32* ranks, u32* bars,
             const float* __restrict__ wtblr, const float* __restrict__ worient,
             const float* __restrict__ ctblr,
             const int* p_sw, const int* p_sh, const int* p_ow, const int* p_oh,
             u64* sortedW, u64* sortedC, float4* aabbW, float4* aabbC,
             float* out_wb, float* out_cb){
  __shared__ u64 chunk[256];
  const int tid = threadIdx.x;
  u32 CW = stW->counter; if (CW > CAPW) CW = CAPW;
  u32 CC = stC->counter; if (CC > CAPC) CC = CAPC;
  // ---- boxes for this block's 64 slots -> registers (wave 0 only) ----
  bool live = false; bool myW = false; u64 my = 0ull;
  float bx0,bx1,bx2,bx3,bx4,bx5,bx6,bx7,bx8;
  float4 av;
  if (tid < 64){
    int t = blockIdx.x*64 + tid;            // 128*64 == CAPW+CAPC exactly
    myW = (t < CAPW);
    int slot = myW ? t : t - CAPW;
    u32 C = myW ? CW : CC;
    if (slot < (int)C){
      live = true;
      my = (myW ? candW : candC)[slot];
      u32 idx = 0xFFFFFFFFu - (u32)(my & 0xFFFFFFFFull);
      float score = __uint_as_float((u32)(my>>32));
      float swf = (float)(*p_sw) * 4.0f;    // WORD_STRIDE == CHAR_STRIDE == 4
      float shf = (float)(*p_sh) * 4.0f;
      float owm = (float)(*p_ow) - 1.0f, ohm = (float)(*p_oh) - 1.0f;
      const float* tblr = myW ? wtblr : ctblr;
      float tt2 = tblr[idx], bb = tblr[N_PIX+idx], ll = tblr[2*N_PIX+idx], rr = tblr[3*N_PIX+idx];
      float xf = (float)(idx & 511u), yf = (float)(idx >> 9);
      float c = 1.0f, sn = 0.0f;
      if (myW){ float o = worient[idx]; c = cosf(o); sn = sinf(o); }
      float x1 = swf*(xf - ll), x2 = swf*(xf + rr);
      float y1 = shf*(yf - tt2), y2 = shf*(yf + bb);
      float ax = swf*xf, ay = shf*yf;
      float cx[4] = {x1,x2,x2,x1};
      float cy[4] = {y1,y1,y2,y2};
      float rx[4], ry[4];
      #pragma unroll
      for (int q=0;q<4;q++){
        float dx = cx[q]-ax, dy = cy[q]-ay;
        rx[q] = ax + dx*c - dy*sn;
        ry[q] = ay + dx*sn + dy*c;
      }
      float minx = fminf(fminf(rx[0],rx[1]),fminf(rx[2],rx[3]));
      float maxx = fmaxf(fmaxf(rx[0],rx[1]),fmaxf(rx[2],rx[3]));
      float miny = fminf(fminf(ry[0],ry[1]),fminf(ry[2],ry[3]));
      float maxy = fmaxf(fmaxf(ry[0],ry[1]),fmaxf(ry[2],ry[3]));
      av = make_float4(minx,miny,maxx,maxy);
      bx0 = fminf(fmaxf(rintf(rx[0]),0.0f), owm); bx1 = fminf(fmaxf(rintf(ry[0]),0.0f), ohm);
      bx2 = fminf(fmaxf(rintf(rx[1]),0.0f), owm); bx3 = fminf(fmaxf(rintf(ry[1]),0.0f), ohm);
      bx4 = fminf(fmaxf(rintf(rx[2]),0.0f), owm); bx5 = fminf(fmaxf(rintf(ry[2]),0.0f), ohm);
      bx6 = fminf(fmaxf(rintf(rx[3]),0.0f), owm); bx7 = fminf(fmaxf(rintf(ry[3]),0.0f), ohm);
      bx8 = score;
    }
  }
  // ---- tiled rank count: 512-slot groups x 256-key chunks, whole grid ----
  {
    int gW = (int)((CW + 511) >> 9), hW = (int)((CW + 255) >> 8);
    int gC = (int)((CC + 511) >> 9), hC = (int)((CC + 255) >> 8);
    int tilesW = gW*hW, tiles = tilesW + gC*hC;
    for (int t = blockIdx.x; t < tiles; t += NBLK){
      bool isW = (t < tilesW);
      int tt = isW ? t : t - tilesW;
      int h  = isW ? hW : hC;
      u32 C  = isW ? CW : CC;
      const u64* cand = isW ? candW : candC;
      u32* rk = isW ? ranks : (ranks + CAPW);
      int sg = tt / h, ch = tt - sg*h;
      __syncthreads();                      // LDS reuse guard
      if (tid < 256){ int ci = ch*256 + tid; chunk[tid] = (ci < (int)C) ? cand[ci] : 0ull; }
      __syncthreads();
      int slot = sg*BS + tid;
      if (slot < (int)C){
        u64 m2 = cand[slot];
        int cnt = 0;
        const ulonglong2* cp = (const ulonglong2*)chunk;
        #pragma unroll 8
        for (int i2=0;i2<128;i2++){ ulonglong2 v = cp[i2]; cnt += (v.x > m2) + (v.y > m2); }
        if (cnt) atomicAdd(&rk[slot], (u32)cnt);
      }
    }
  }
  // ---- full barrier (ranks complete) ----
  __syncthreads();
  if (tid==0){
    __hip_atomic_fetch_add(&bars[3],1u,__ATOMIC_ACQ_REL,__HIP_MEMORY_SCOPE_AGENT);
    while (__hip_atomic_load(&bars[3], __ATOMIC_ACQUIRE, __HIP_MEMORY_SCOPE_AGENT) < (u32)NBLK)
      __builtin_amdgcn_s_sleep(2);
  }
  __syncthreads();
  // ---- permute from registers to sorted order ----
  if (live){
    int t = blockIdx.x*64 + tid;
    int rank = (int)ranks[t];
    int K = myW ? KW : KC;
    if (rank < K){
      (myW ? sortedW : sortedC)[rank] = my;
      (myW ? aabbW : aabbC)[rank] = av;
      float* ob = myW ? out_wb : out_cb;
      ob[rank*9+0]=bx0; ob[rank*9+1]=bx1; ob[rank*9+2]=bx2; ob[rank*9+3]=bx3;
      ob[rank*9+4]=bx4; ob[rank*9+5]=bx5; ob[rank*9+6]=bx6; ob[rank*9+7]=bx7;
      ob[rank*9+8]=bx8;
    }
  }
}

template<int W>
__device__ __forceinline__ void sup_row(int j, int lane, const float4* __restrict__ aabb,
                                        u64* __restrict__ supT, u32* __restrict__ rm){
  float4 bj = aabb[j];
  float aj = fmaxf(bj.z-bj.x,0.0f)*fmaxf(bj.w-bj.y,0.0f);
  u32 m = 0;
  #pragma unroll 4
  for (int w=0; w<W; w++){
    int i = w*64 + lane;
    float4 bi = aabb[i];
    float ai = fmaxf(bi.z-bi.x,0.0f)*fmaxf(bi.w-bi.y,0.0f);
    float ix1=fmaxf(bi.x,bj.x), iy1=fmaxf(bi.y,bj.y);
    float ix2=fminf(bi.z,bj.z), iy2=fminf(bi.w,bj.w);
    float inter = fmaxf(ix2-ix1,0.0f)*fmaxf(iy2-iy1,0.0f);
    float iou = inter/(ai+aj-inter+1e-6f);
    bool bit = (iou > IOU_THR) && (i < j);
    u64 b = __ballot(bit);
    if (b){ if (lane==0) supT[(size_t)j*W + w] = b; m |= 1u << w; }
  }
  if (lane==0) rm[j] = m;
}

// NMS Jacobi fixpoint (unique fixed point == greedy NMS result)
template<int K, int W>
__device__ void nms_body(u64* kw, int* changed,
                         const u64* __restrict__ supT, const u32* __restrict__ rm,
                         const u64* __restrict__ sorted, float* __restrict__ keep){
  const int tid = threadIdx.x;
  const int lane = tid & 63, wv = tid >> 6;
  constexpr int NB = (K + BS - 1)/BS;
  if (tid < W) kw[tid] = ~0ull;
  __syncthreads();
  for(;;){
    if (tid==0) *changed = 0;
    __syncthreads();
    bool nb[NB];
    #pragma unroll
    for (int q=0;q<NB;q++){
      int j = q*BS + tid;
      bool ok = (j < K);
      u64 su = 0ull;
      if (ok){
        u32 m = rm[j];
        while (m){ int w = __ffs(m)-1; m &= m-1u; su |= supT[(size_t)j*W + w] & kw[w]; }
      }
      nb[q] = ok && (su == 0ull);
    }
    __syncthreads();
    #pragma unroll
    for (int q=0;q<NB;q++){
      int wi = q*(BS/64) + wv;
      u64 b = __ballot(nb[q]);
      if (lane==0 && wi < W){
        if (b != kw[wi]){ kw[wi] = b; *changed = 1; }
      }
    }
    __syncthreads();
    int ch = *changed;
    __syncthreads();
    if (!ch) break;
  }
  #pragma unroll
  for (int q=0;q<NB;q++){
    int j = q*BS + tid;
    if (j < K){
      u64 key = sorted[j];
      bool pos = ((u32)(key>>32)) != 0u;
      bool kp = (((kw[j>>6] >> (j&63)) & 1ull) != 0ull) && pos;
      keep[j] = kp ? 1.0f : 0.0f;
    }
  }
}

// D4: sup (all blocks) + gather (blocks >=2, pre-arrival) -> partial barrier -> nms (blocks 0,1)
__global__ __launch_bounds__(BS)
void k4_tail(const float4* __restrict__ aabbW, const float4* __restrict__ aabbC,
             u64* supTW, u64* supTC, u32* rmW, u32* rmC, u32* bars,
             const u64* __restrict__ sortedW, const u64* __restrict__ sortedC,
             const float* __restrict__ ccls, float* __restrict__ out_cs,
             float* out_wk, float* out_ck){
  __shared__ u64 kw[KC/64];
  __shared__ int changed;
  const int tid = threadIdx.x;
  const int gtid = blockIdx.x*BS + tid;
  const int lane = tid & 63;
  int gw = gtid >> 6;                        // 1024 waves, 2-3 rows each
  for (int row = gw; row < KW+KC; row += GSZ/64){
    if (row < KW) sup_row<KW/64>(row, lane, aabbW, supTW, rmW);
    else          sup_row<KC/64>(row-KW, lane, aabbC, supTC, rmC);
  }
  if (blockIdx.x >= 2){
    // class gather before arrival (avoids HBM contention with the nms fixpoint)
    for (int t = (blockIdx.x-2)*BS + tid; t < KC*NUM_CLS; t += (NBLK-2)*BS){
      int k = t / NUM_CLS;
      int c = t - k*NUM_CLS;
      u32 idx = 0xFFFFFFFFu - (u32)(sortedC[k] & 0xFFFFFFFFull);
      out_cs[t] = ccls[(size_t)c*N_PIX + idx];
    }
  }
  __syncthreads();
  if (tid==0) __hip_atomic_fetch_add(&bars[2],1u,__ATOMIC_ACQ_REL,__HIP_MEMORY_SCOPE_AGENT);
  if (blockIdx.x >= 2) return;
  if (tid==0){
    while (__hip_atomic_load(&bars[2], __ATOMIC_ACQUIRE, __HIP_MEMORY_SCOPE_AGENT) < (u32)NBLK)
      __builtin_amdgcn_s_sleep(2);
  }
  __syncthreads();
  if (blockIdx.x == 0) nms_body<KW, KW/64>(kw, &changed, supTW, rmW, sortedW, out_wk);
  else                 nms_body<KC, KC/64>(kw, &changed, supTC, rmC, sortedC, out_ck);
}

extern "C" void kernel_launch(void* const* d_in, const int* in_sizes, int n_in,
                              void* d_out, int out_size, void* d_ws, size_t ws_size,
                              hipStream_t stream) {
  const float* wfg     = (const float*)d_in[0];
  const float* wtblr   = (const float*)d_in[1];
  const float* worient = (const float*)d_in[2];
  const float* cfg     = (const float*)d_in[3];
  const float* ctblr   = (const float*)d_in[4];
  const float* ccls    = (const float*)d_in[5];
  const int* p_sw = (const int*)d_in[6];
  const int* p_sh = (const int*)d_in[7];
  const int* p_ow = (const int*)d_in[8];
  const int* p_oh = (const int*)d_in[9];

  // ws layout (phase-overlayed; all accesses < 631824 B)
  char* ws = (char*)d_ws;
  u64* candW   = (u64*)(ws + 0);        // dies after k3_rank; then supTW
  u64* candC   = (u64*)(ws + 32768);    // dies after k3_rank; then supTC
  u64* supTW   = (u64*)(ws + 0);
  u64* supTC   = (u64*)(ws + 32768);    // spans to 557056
  u32* ranks   = (u32*)(ws + 65536);    // [CAPW+CAPC]; dies after k3_rank (under supTC span)
  u64* sortedW = (u64*)(ws + 557056);
  u64* sortedC = (u64*)(ws + 561152);
  float4* aabbW= (float4*)(ws + 577536);
  float4* aabbC= (float4*)(ws + 585728);
  u32* rmW     = (u32*)(ws + 618496);
  u32* rmC     = (u32*)(ws + 620544);
  SelState* stW= (SelState*)(ws + 628736);
  u32* bars    = (u32*)(ws + 630016);
  SelState* stC= (SelState*)(ws + 630784);

  float* out = (float*)d_out;
  float* out_cb = out;                          // char bboxes 2048*9
  float* out_cs = out + KC*9;                   // char scores 2048*68
  float* out_wb = out + KC*9 + KC*NUM_CLS;      // word bboxes 512*9
  float* out_wk = out_wb + KW*9;                // wkeep 512
  float* out_ck = out_wk + KW;                  // ckeep 2048

  k0_init<<<1, 256, 0, stream>>>(stW, stC, bars);
  k1_hist<<<NBLK, BS, 0, stream>>>(wfg, cfg, stW, stC, bars, ranks);
  k2_compact<<<NBLK, BS, 0, stream>>>(wfg, cfg, stW, stC, candW, candC);
  k3_rank<<<NBLK, BS, 0, stream>>>(stW, stC, candW, candC, ranks, bars,
                                   wtblr, worient, ctblr, p_sw, p_sh, p_ow, p_oh,
                                   sortedW, sortedC, aabbW, aabbC, out_wb, out_cb);
  k4_tail<<<NBLK, BS, 0, stream>>>(aabbW, aabbC, supTW, supTC, rmW, rmC, bars,
                                   sortedW, sortedC, ccls, out_cs, out_wk, out_ck);
}